// Round 7
// baseline (546.785 us; speedup 1.0000x reference)
//
#include <hip/hip_runtime.h>

// MFMA-based fully-fused 5-layer bidirectional GRU -- high-occupancy version.
//
// Round-6 analysis: 2 waves/SIMD (40KB LDS -> 4 blocks/CU) made the kernel
// latency-bound at its own floor (VALUBusy 60%, period ~667cy vs issue 2x210).
// Fix: move ONE ping-pong sequence buffer to a static global array; LDS drops
// to one 19.2KB buffer -> 8 blocks/CU = 4 waves/SIMD = 2x the chains hiding
// each other's stalls. Layer dataflow: L0: x(global)->S(LDS); L1: S->G(HBM);
// L2: G->S; L3: S->G; L4: G->out. Global reads are prefetched 2 positions
// ahead on vmcnt (decoupled from the bpermute's lgkmcnt); global traffic
// (~1GB) is mostly L2/L3-resident (each block re-reads its own 19KB one layer
// later). Non-temporal ops bypass L1 (coherence + no thrash).
//
// Per step, ONE v_mfma_f32_32x32x16_f16 computes every gate pre-activation
// for 32 batch elems of one direction (wave0 = fwd, wave1 = bwd):
//   A (32x16 const): row r = 8q+4h+g holds unit u=2q+1-h, gate g in
//     {r,z,i_n,h_n}; k0..9 = W_ih (10 input ch), k10..14 = W_hh. i_n/h_n in
//     separate rows so n = tanh(i_n + r*h_n) stays exact; exp2 scales folded.
//   B (16x32 per step): col = batch; k0..9 = prev-layer output, k10..14 =
//     own h (register recurrence).  C = bias fragment (re-added free).
// D layout (row=(reg&3)+8*(reg>>2)+4*half): lane quad q = unit 2q+1-half ->
// half1 owns u{0,2,4}, needs only u{1,3} from half0: ONE ds_bpermute + 2
// v_perm per step (verified r2/r6; permlane32_swap failed r3/r4 -> banned).
//
// Sequences: f16 pair-planes seq[t][unit][batch], fwd lo / bwd hi halfword.
// Layer-4 bwd needs only ys[T-1] = its first step. LDS: 19200 B.

#define NB 262144
#define T 30
#define NBLK (NB / 32)
#define SEQW (T * 5 * 32)          // u32 per per-block sequence buffer

typedef _Float16 f16x8 __attribute__((ext_vector_type(8)));
typedef float f32x16 __attribute__((ext_vector_type(16)));

__device__ unsigned g_seq[(unsigned long long)NBLK * SEQW];   // 157 MB

#define SIG_SCALE  (-1.4426950408889634f)   // -log2(e)
#define TANH_SCALE ( 2.8853900817779268f)   // 2*log2(e)

__device__ __forceinline__ float sig_s(float xs) {
    return __builtin_amdgcn_rcpf(1.0f + __builtin_amdgcn_exp2f(xs));
}
__device__ __forceinline__ float tanh_s(float xs) {
    return fmaf(-2.0f, __builtin_amdgcn_rcpf(1.0f + __builtin_amdgcn_exp2f(xs)), 1.0f);
}
__device__ __forceinline__ unsigned packh(_Float16 a, _Float16 b) {
    union { _Float16 f; unsigned short s; } ua, ub;
    ua.f = a; ub.f = b;
    return (unsigned)ua.s | ((unsigned)ub.s << 16);
}
__device__ __forceinline__ unsigned ntl(const unsigned* p) {
    return __builtin_nontemporal_load(p);
}
__device__ __forceinline__ void nth(_Float16 v, _Float16* p) {
    union { _Float16 f; unsigned short s; } u; u.f = v;
    __builtin_nontemporal_store(u.s, (unsigned short*)p);
}

// One direction of one layer. seqR/seqW: [T][5][32] u32 pair-plane buffers
// (LDS or global per G_R/G_W); xg: per-block x base (layer 0 only).
template <bool IS_L0, int NT, bool WRITE, bool STORE, bool G_R, bool G_W>
__device__ __forceinline__ void run_layer(
    const float* __restrict__ wih, const float* __restrict__ whh,
    const float* __restrict__ bih, const float* __restrict__ bhh,
    const unsigned* seqR, unsigned* seqW, const float* xg,
    float* outp, const int d, const int lane)
{
    const int lr   = lane & 31;    // A row / B,D column (batch)
    const int half = lane >> 5;    // k-half for A/B; D-row half bit

    // ---- A fragment: row lr = 8q+4h+g -> unit u_r = 2q+1-h, gate g ----
    const int q_r = lr >> 3;
    const int h_r = (lr >> 2) & 1;
    const int g   = lr & 3;        // 0=r 1=z 2=i_n 3=h_n
    const int u_r = 2 * q_r + 1 - h_r;
    const bool rv = (q_r < 3) && (u_r < 5);   // rows 16-19 & 24-31 zero

    f16x8 af;
#pragma unroll
    for (int e = 0; e < 8; e++) {
        const int k = 8 * half + e;           // elem e <-> k = 8*half + e
        float v = 0.f;
        if (rv) {
            if (!IS_L0) {
                if (k < 10) {                       // input channels
                    const int j = (k & 1) * 5 + (k >> 1);   // concat col
                    if (g == 0)      v = SIG_SCALE  * wih[u_r * 10 + j];
                    else if (g == 1) v = SIG_SCALE  * wih[(5 + u_r) * 10 + j];
                    else if (g == 2) v = TANH_SCALE * wih[(10 + u_r) * 10 + j];
                } else if (k < 15) {                // own-dir hidden
                    const int uh = k - 10;
                    if (g == 0)      v = SIG_SCALE  * whh[u_r * 5 + uh];
                    else if (g == 1) v = SIG_SCALE  * whh[(5 + u_r) * 5 + uh];
                    else if (g == 3) v = TANH_SCALE * whh[(10 + u_r) * 5 + uh];
                }
            } else {
                if (k == 0) {                       // input dim 1
                    if (g == 0)      v = SIG_SCALE  * wih[u_r];
                    else if (g == 1) v = SIG_SCALE  * wih[5 + u_r];
                    else if (g == 2) v = TANH_SCALE * wih[10 + u_r];
                } else if (k >= 10 && k < 15) {
                    const int uh = k - 10;
                    if (g == 0)      v = SIG_SCALE  * whh[u_r * 5 + uh];
                    else if (g == 1) v = SIG_SCALE  * whh[(5 + u_r) * 5 + uh];
                    else if (g == 3) v = TANH_SCALE * whh[(10 + u_r) * 5 + uh];
                }
            }
        }
        af[e] = (_Float16)v;
    }

    // ---- bias fragment (C): quad q -> unit u = 2q+1-half ----
    f32x16 bc;
#pragma unroll
    for (int q = 0; q < 4; q++) {
        const int u = 2 * q + 1 - half;
        float b0 = 0.f, b1 = 0.f, b2 = 0.f, b3 = 0.f;
        if (q < 3 && u < 5) {
            b0 = SIG_SCALE  * (bih[u] + bhh[u]);
            b1 = SIG_SCALE  * (bih[5 + u] + bhh[5 + u]);
            b2 = TANH_SCALE * bih[10 + u];
            b3 = TANH_SCALE * bhh[10 + u];
        }
        bc[4 * q + 0] = b0; bc[4 * q + 1] = b1;
        bc[4 * q + 2] = b2; bc[4 * q + 3] = b3;
    }

    // ---- step state ----
    const int sdir = d ? -1 : 1;
    const int p0   = d ? (T - 1) : 0;
    const unsigned* rbase = seqR + p0 * 160 + lr;
    const int r0off = half ? 128 : 0;            // half1 reads plane4 (ch8,9)
    _Float16* wbase = (_Float16*)seqW + p0 * 320 + lr * 2 + d;
    const int rstep = sdir * 160, wstep = sdir * 320;
    const int paddr = (lane ^ 32) << 2;          // cross-half partner

    // h0 = unit (1-half), h1 = unit (3-half), h2 = unit 4 (half1 only)
    float h0 = 0.f, h1 = 0.f, h2 = 0.f;
    unsigned pb1 = 0, pb2 = 0, pb3 = 0;          // h-slots of B (k10..15)

    auto step = [&](unsigned B0, unsigned B1, unsigned B2, unsigned B3) {
        union { f16x8 v; unsigned u[4]; } B;
        B.u[0] = B0;
        B.u[1] = half ? pb1 : B1;
        B.u[2] = half ? pb2 : B2;
        B.u[3] = half ? pb3 : B3;

        const f32x16 D = __builtin_amdgcn_mfma_f32_32x32x16_f16(af, B.v, bc, 0, 0, 0);

        float r, z, n;
        r = sig_s(D[0]); z = sig_s(D[1]);
        n = tanh_s(fmaf(r, D[3], D[2]));
        h0 = fmaf(z, h0 - n, n);
        r = sig_s(D[4]); z = sig_s(D[5]);
        n = tanh_s(fmaf(r, D[7], D[6]));
        h1 = fmaf(z, h1 - n, n);

        // single cross-half exchange, issued early; hides under u4 chain
        const _Float16 q0f = (_Float16)h0, q1f = (_Float16)h1;
        const unsigned pks = packh(q0f, q1f);
        const unsigned o = (unsigned)__builtin_amdgcn_ds_bpermute(paddr, (int)pks);

        r = sig_s(D[8]); z = sig_s(D[9]);
        n = tanh_s(fmaf(r, D[11], D[10]));
        h2 = fmaf(z, h2 - n, n);                 // zero-rows on half0: harmless
        const _Float16 q2f = (_Float16)h2;

        pb1 = __builtin_amdgcn_perm(pks, o, 0x01000504u);  // [h_u0, h_u1]
        pb2 = __builtin_amdgcn_perm(pks, o, 0x03020706u);  // [h_u2, h_u3]
        pb3 = packh(q2f, (_Float16)0.f);                   // [h_u4, 0]

        if constexpr (WRITE) {
            if constexpr (G_W) {
                nth(q0f, wbase + (1 - half) * 64);
                nth(q1f, wbase + (3 - half) * 64);
                if (half) nth(q2f, wbase + 4 * 64);
            } else {
                wbase[(1 - half) * 64] = q0f;
                wbase[(3 - half) * 64] = q1f;
                if (half) wbase[4 * 64] = q2f;
            }
            wbase += wstep;
        }
    };

    if constexpr (IS_L0) {
        // x direct from global, 1-step prefetch; lines L1-resident across steps
        const float* xp = xg + lr * T + p0;
        float xf = *xp;
        for (int s = 0; s < NT; s++) {
            const unsigned xv = packh((_Float16)xf, (_Float16)0.f);
            if (s + 1 < NT) { xp += sdir; xf = *xp; }
            step(half ? 0u : xv, 0u, 0u, 0u);
        }
    } else if constexpr (!G_R) {
        // LDS reads, 1-step prefetch
        const unsigned* rb = rbase;
        unsigned c0 = rb[r0off], c1 = rb[32], c2 = rb[64], c3 = rb[96];
        for (int s = 0; s < NT; s++) {
            const unsigned t0 = c0, t1 = c1, t2 = c2, t3 = c3;
            if (s + 1 < NT) {
                rb += rstep;
                c0 = rb[r0off]; c1 = rb[32]; c2 = rb[64]; c3 = rb[96];
            }
            step(t0, t1, t2, t3);
        }
    } else if constexpr (NT == 1) {
        // layer-4 bwd: single step
        const unsigned a0 = ntl(rbase + r0off), a1 = ntl(rbase + 32),
                       a2 = ntl(rbase + 64),   a3 = ntl(rbase + 96);
        step(a0, a1, a2, a3);
    } else {
        // global reads: two reg sets, prefetch 2 positions ahead (vmcnt)
        const unsigned* rn = rbase;
        unsigned a0 = ntl(rn + r0off), a1 = ntl(rn + 32), a2 = ntl(rn + 64), a3 = ntl(rn + 96);
        rn += rstep;
        unsigned b0 = ntl(rn + r0off), b1 = ntl(rn + 32), b2 = ntl(rn + 64), b3 = ntl(rn + 96);
        rn += rstep;
        for (int s = 0; s < NT; s += 2) {
            step(a0, a1, a2, a3);
            if (s + 2 < NT) {
                a0 = ntl(rn + r0off); a1 = ntl(rn + 32); a2 = ntl(rn + 64); a3 = ntl(rn + 96);
                rn += rstep;
            }
            step(b0, b1, b2, b3);
            if (s + 3 < NT) {
                b0 = ntl(rn + r0off); b1 = ntl(rn + 32); b2 = ntl(rn + 64); b3 = ntl(rn + 96);
                rn += rstep;
            }
        }
    }

    if constexpr (STORE) {               // ys[T-1] for this direction
        outp[1 - half] = h0;
        outp[3 - half] = h1;
        if (half) outp[4] = h2;
    }
}

__global__ void __launch_bounds__(128, 4) gru_all(
    const float* __restrict__ x,
    const float* __restrict__ wih0, const float* __restrict__ whh0,
    const float* __restrict__ bih0, const float* __restrict__ bhh0,
    const float* __restrict__ wihL, const float* __restrict__ whhL,
    const float* __restrict__ bihL, const float* __restrict__ bhhL,
    float* __restrict__ out)
{
    __shared__ unsigned S[T][5][32];             // 19200 B -> 8 blocks/CU

    const int tid  = threadIdx.x;
    const int d    = tid >> 6;                   // wave0 = fwd, wave1 = bwd
    const int lane = tid & 63;
    const int lr   = lane & 31;
    const long base = (long)blockIdx.x * 32;

    const float* xg = x + base * T;
    unsigned* G = g_seq + (unsigned long long)blockIdx.x * SEQW;

    // L0: x -> S
    run_layer<true, T, true, false, false, false>(
        wih0 + d * 15, whh0 + d * 75, bih0 + d * 15, bhh0 + d * 15,
        nullptr, &S[0][0][0], xg, nullptr, d, lane);
    __syncthreads();

    // L1: S -> G
    run_layer<false, T, true, false, false, true>(
        wihL + (0 + d) * 150, whhL + (0 + d) * 75, bihL + (0 + d) * 15, bhhL + (0 + d) * 15,
        &S[0][0][0], G, nullptr, nullptr, d, lane);
    __syncthreads();

    // L2: G -> S
    run_layer<false, T, true, false, true, false>(
        wihL + (2 + d) * 150, whhL + (2 + d) * 75, bihL + (2 + d) * 15, bhhL + (2 + d) * 15,
        G, &S[0][0][0], nullptr, nullptr, d, lane);
    __syncthreads();

    // L3: S -> G
    run_layer<false, T, true, false, false, true>(
        wihL + (4 + d) * 150, whhL + (4 + d) * 75, bihL + (4 + d) * 15, bhhL + (4 + d) * 15,
        &S[0][0][0], G, nullptr, nullptr, d, lane);
    __syncthreads();

    // L4: G -> out; fwd runs 30 steps, bwd needs only its first step
    {
        float* op = out + (base + lr) * 10 + d * 5;
        if (d == 0)
            run_layer<false, T, false, true, true, false>(
                wihL + 6 * 150, whhL + 6 * 75, bihL + 6 * 15, bhhL + 6 * 15,
                G, nullptr, nullptr, op, d, lane);
        else
            run_layer<false, 1, false, true, true, false>(
                wihL + 7 * 150, whhL + 7 * 75, bihL + 7 * 15, bhhL + 7 * 15,
                G, nullptr, nullptr, op, d, lane);
    }
}

extern "C" void kernel_launch(void* const* d_in, const int* in_sizes, int n_in,
                              void* d_out, int out_size, void* d_ws, size_t ws_size,
                              hipStream_t stream) {
    const float* x    = (const float*)d_in[0];
    const float* wih0 = (const float*)d_in[1];
    const float* whh0 = (const float*)d_in[2];
    const float* bih0 = (const float*)d_in[3];
    const float* bhh0 = (const float*)d_in[4];
    const float* wihL = (const float*)d_in[5];
    const float* whhL = (const float*)d_in[6];
    const float* bihL = (const float*)d_in[7];
    const float* bhhL = (const float*)d_in[8];
    float* out = (float*)d_out;

    gru_all<<<NBLK, 128, 0, stream>>>(x, wih0, whh0, bih0, bhh0,
                                      wihL, whhL, bihL, bhhL, out);
}

// Round 8
// 448.816 us; speedup vs baseline: 1.2183x; 1.2183x over previous
//
#include <hip/hip_runtime.h>

// MFMA-based fully-fused 5-layer bidirectional GRU -- high-occupancy version.
//
// Round-7 lesson: non-temporal global ops bypassed L2, producing 920 MB HBM
// traffic/dispatch (677 MB writes = 2.1x ideal from partial-line RMW) and
// ~900cy read latency in L2/L4 -> waves stalled, VALUBusy stuck at 63%.
// This round: PLAIN cached loads/stores. The per-block G buffer (19.2 KB,
// written layer l, re-read by the same block layer l+1) is L2-temporal;
// partial-line stores merge in L2; same-CU L1 coherence is HW-maintained
// (write-through), already correctness-proven in r7.
//
// Structure (r6/r7, verified): block = 2 waves (wave0 fwd, wave1 bwd),
// 32 batch elems. One LDS seq buffer (19.2 KB -> 8 blocks/CU = 4 waves/SIMD);
// second buffer in static global. Dataflow: L0: x->S; L1: S->G; L2: G->S;
// L3: S->G; L4: G->out (bwd needs only its first step).
//
// Per step, ONE v_mfma_f32_32x32x16_f16 computes every gate pre-activation
// for 32 batch elems of one direction:
//   A (32x16 const): row r = 8q+4h+g holds unit u=2q+1-h, gate g in
//     {r,z,i_n,h_n}; k0..9 = W_ih (10 input ch), k10..14 = W_hh. i_n/h_n in
//     separate rows so n = tanh(i_n + r*h_n) stays exact; exp2 scales folded.
//   B (16x32 per step): col = batch; k0..9 = prev-layer output, k10..14 =
//     own h (register recurrence).  C = bias fragment (re-added free).
// D layout (row=(reg&3)+8*(reg>>2)+4*half): lane quad q = unit 2q+1-half ->
// half1 owns u{0,2,4}, needs only u{1,3} from half0: ONE ds_bpermute + 2
// v_perm per step (verified r2/r6; permlane32_swap failed r3/r4 -> banned).
//
// Sequences: f16 pair-planes seq[t][unit][batch], fwd lo / bwd hi halfword.

#define NB 262144
#define T 30
#define NBLK (NB / 32)
#define SEQW (T * 5 * 32)          // u32 per per-block sequence buffer

typedef _Float16 f16x8 __attribute__((ext_vector_type(8)));
typedef float f32x16 __attribute__((ext_vector_type(16)));

__device__ unsigned g_seq[(unsigned long long)NBLK * SEQW];   // 157 MB

#define SIG_SCALE  (-1.4426950408889634f)   // -log2(e)
#define TANH_SCALE ( 2.8853900817779268f)   // 2*log2(e)

__device__ __forceinline__ float sig_s(float xs) {
    return __builtin_amdgcn_rcpf(1.0f + __builtin_amdgcn_exp2f(xs));
}
__device__ __forceinline__ float tanh_s(float xs) {
    return fmaf(-2.0f, __builtin_amdgcn_rcpf(1.0f + __builtin_amdgcn_exp2f(xs)), 1.0f);
}
__device__ __forceinline__ unsigned packh(_Float16 a, _Float16 b) {
    union { _Float16 f; unsigned short s; } ua, ub;
    ua.f = a; ub.f = b;
    return (unsigned)ua.s | ((unsigned)ub.s << 16);
}

// One direction of one layer. seqR/seqW: [T][5][32] u32 pair-plane buffers
// (LDS or global per G_R/G_W); xg: per-block x base (layer 0 only).
template <bool IS_L0, int NT, bool WRITE, bool STORE, bool G_R, bool G_W>
__device__ __forceinline__ void run_layer(
    const float* __restrict__ wih, const float* __restrict__ whh,
    const float* __restrict__ bih, const float* __restrict__ bhh,
    const unsigned* seqR, unsigned* seqW, const float* xg,
    float* outp, const int d, const int lane)
{
    const int lr   = lane & 31;    // A row / B,D column (batch)
    const int half = lane >> 5;    // k-half for A/B; D-row half bit

    // ---- A fragment: row lr = 8q+4h+g -> unit u_r = 2q+1-h, gate g ----
    const int q_r = lr >> 3;
    const int h_r = (lr >> 2) & 1;
    const int g   = lr & 3;        // 0=r 1=z 2=i_n 3=h_n
    const int u_r = 2 * q_r + 1 - h_r;
    const bool rv = (q_r < 3) && (u_r < 5);   // rows 16-19 & 24-31 zero

    f16x8 af;
#pragma unroll
    for (int e = 0; e < 8; e++) {
        const int k = 8 * half + e;           // elem e <-> k = 8*half + e
        float v = 0.f;
        if (rv) {
            if (!IS_L0) {
                if (k < 10) {                       // input channels
                    const int j = (k & 1) * 5 + (k >> 1);   // concat col
                    if (g == 0)      v = SIG_SCALE  * wih[u_r * 10 + j];
                    else if (g == 1) v = SIG_SCALE  * wih[(5 + u_r) * 10 + j];
                    else if (g == 2) v = TANH_SCALE * wih[(10 + u_r) * 10 + j];
                } else if (k < 15) {                // own-dir hidden
                    const int uh = k - 10;
                    if (g == 0)      v = SIG_SCALE  * whh[u_r * 5 + uh];
                    else if (g == 1) v = SIG_SCALE  * whh[(5 + u_r) * 5 + uh];
                    else if (g == 3) v = TANH_SCALE * whh[(10 + u_r) * 5 + uh];
                }
            } else {
                if (k == 0) {                       // input dim 1
                    if (g == 0)      v = SIG_SCALE  * wih[u_r];
                    else if (g == 1) v = SIG_SCALE  * wih[5 + u_r];
                    else if (g == 2) v = TANH_SCALE * wih[10 + u_r];
                } else if (k >= 10 && k < 15) {
                    const int uh = k - 10;
                    if (g == 0)      v = SIG_SCALE  * whh[u_r * 5 + uh];
                    else if (g == 1) v = SIG_SCALE  * whh[(5 + u_r) * 5 + uh];
                    else if (g == 3) v = TANH_SCALE * whh[(10 + u_r) * 5 + uh];
                }
            }
        }
        af[e] = (_Float16)v;
    }

    // ---- bias fragment (C): quad q -> unit u = 2q+1-half ----
    f32x16 bc;
#pragma unroll
    for (int q = 0; q < 4; q++) {
        const int u = 2 * q + 1 - half;
        float b0 = 0.f, b1 = 0.f, b2 = 0.f, b3 = 0.f;
        if (q < 3 && u < 5) {
            b0 = SIG_SCALE  * (bih[u] + bhh[u]);
            b1 = SIG_SCALE  * (bih[5 + u] + bhh[5 + u]);
            b2 = TANH_SCALE * bih[10 + u];
            b3 = TANH_SCALE * bhh[10 + u];
        }
        bc[4 * q + 0] = b0; bc[4 * q + 1] = b1;
        bc[4 * q + 2] = b2; bc[4 * q + 3] = b3;
    }

    // ---- step state ----
    const int sdir = d ? -1 : 1;
    const int p0   = d ? (T - 1) : 0;
    const unsigned* rbase = seqR + p0 * 160 + lr;
    const int r0off = half ? 128 : 0;            // half1 reads plane4 (ch8,9)
    _Float16* wbase = (_Float16*)seqW + p0 * 320 + lr * 2 + d;
    const int rstep = sdir * 160, wstep = sdir * 320;
    const int paddr = (lane ^ 32) << 2;          // cross-half partner

    // h0 = unit (1-half), h1 = unit (3-half), h2 = unit 4 (half1 only)
    float h0 = 0.f, h1 = 0.f, h2 = 0.f;
    unsigned pb1 = 0, pb2 = 0, pb3 = 0;          // h-slots of B (k10..15)

    auto step = [&](unsigned B0, unsigned B1, unsigned B2, unsigned B3) {
        union { f16x8 v; unsigned u[4]; } B;
        B.u[0] = B0;
        B.u[1] = half ? pb1 : B1;
        B.u[2] = half ? pb2 : B2;
        B.u[3] = half ? pb3 : B3;

        const f32x16 D = __builtin_amdgcn_mfma_f32_32x32x16_f16(af, B.v, bc, 0, 0, 0);

        float r, z, n;
        r = sig_s(D[0]); z = sig_s(D[1]);
        n = tanh_s(fmaf(r, D[3], D[2]));
        h0 = fmaf(z, h0 - n, n);
        r = sig_s(D[4]); z = sig_s(D[5]);
        n = tanh_s(fmaf(r, D[7], D[6]));
        h1 = fmaf(z, h1 - n, n);

        // single cross-half exchange, issued early; hides under u4 chain
        const _Float16 q0f = (_Float16)h0, q1f = (_Float16)h1;
        const unsigned pks = packh(q0f, q1f);
        const unsigned o = (unsigned)__builtin_amdgcn_ds_bpermute(paddr, (int)pks);

        r = sig_s(D[8]); z = sig_s(D[9]);
        n = tanh_s(fmaf(r, D[11], D[10]));
        h2 = fmaf(z, h2 - n, n);                 // zero-rows on half0: harmless
        const _Float16 q2f = (_Float16)h2;

        pb1 = __builtin_amdgcn_perm(pks, o, 0x01000504u);  // [h_u0, h_u1]
        pb2 = __builtin_amdgcn_perm(pks, o, 0x03020706u);  // [h_u2, h_u3]
        pb3 = packh(q2f, (_Float16)0.f);                   // [h_u4, 0]

        if constexpr (WRITE) {
            wbase[(1 - half) * 64] = q0f;
            wbase[(3 - half) * 64] = q1f;
            if (half) wbase[4 * 64] = q2f;
            wbase += wstep;
        }
    };

    if constexpr (IS_L0) {
        // x direct from global, 1-step prefetch; lines L1-resident across steps
        const float* xp = xg + lr * T + p0;
        float xf = *xp;
        for (int s = 0; s < NT; s++) {
            const unsigned xv = packh((_Float16)xf, (_Float16)0.f);
            if (s + 1 < NT) { xp += sdir; xf = *xp; }
            step(half ? 0u : xv, 0u, 0u, 0u);
        }
    } else if constexpr (!G_R) {
        // LDS reads, 1-step prefetch
        const unsigned* rb = rbase;
        unsigned c0 = rb[r0off], c1 = rb[32], c2 = rb[64], c3 = rb[96];
        for (int s = 0; s < NT; s++) {
            const unsigned t0 = c0, t1 = c1, t2 = c2, t3 = c3;
            if (s + 1 < NT) {
                rb += rstep;
                c0 = rb[r0off]; c1 = rb[32]; c2 = rb[64]; c3 = rb[96];
            }
            step(t0, t1, t2, t3);
        }
    } else if constexpr (NT == 1) {
        // layer-4 bwd: single step
        const unsigned a0 = rbase[r0off], a1 = rbase[32],
                       a2 = rbase[64],   a3 = rbase[96];
        step(a0, a1, a2, a3);
    } else {
        // global reads: two reg sets, prefetch 2 positions ahead (vmcnt)
        const unsigned* rn = rbase;
        unsigned a0 = rn[r0off], a1 = rn[32], a2 = rn[64], a3 = rn[96];
        rn += rstep;
        unsigned b0 = rn[r0off], b1 = rn[32], b2 = rn[64], b3 = rn[96];
        rn += rstep;
        for (int s = 0; s < NT; s += 2) {
            step(a0, a1, a2, a3);
            if (s + 2 < NT) {
                a0 = rn[r0off]; a1 = rn[32]; a2 = rn[64]; a3 = rn[96];
                rn += rstep;
            }
            step(b0, b1, b2, b3);
            if (s + 3 < NT) {
                b0 = rn[r0off]; b1 = rn[32]; b2 = rn[64]; b3 = rn[96];
                rn += rstep;
            }
        }
    }

    if constexpr (STORE) {               // ys[T-1] for this direction
        outp[1 - half] = h0;
        outp[3 - half] = h1;
        if (half) outp[4] = h2;
    }
}

__global__ void __launch_bounds__(128, 4) gru_all(
    const float* __restrict__ x,
    const float* __restrict__ wih0, const float* __restrict__ whh0,
    const float* __restrict__ bih0, const float* __restrict__ bhh0,
    const float* __restrict__ wihL, const float* __restrict__ whhL,
    const float* __restrict__ bihL, const float* __restrict__ bhhL,
    float* __restrict__ out)
{
    __shared__ unsigned S[T][5][32];             // 19200 B -> 8 blocks/CU

    const int tid  = threadIdx.x;
    const int d    = tid >> 6;                   // wave0 = fwd, wave1 = bwd
    const int lane = tid & 63;
    const int lr   = lane & 31;
    const long base = (long)blockIdx.x * 32;

    const float* xg = x + base * T;
    unsigned* G = g_seq + (unsigned long long)blockIdx.x * SEQW;

    // L0: x -> S
    run_layer<true, T, true, false, false, false>(
        wih0 + d * 15, whh0 + d * 75, bih0 + d * 15, bhh0 + d * 15,
        nullptr, &S[0][0][0], xg, nullptr, d, lane);
    __syncthreads();

    // L1: S -> G
    run_layer<false, T, true, false, false, true>(
        wihL + (0 + d) * 150, whhL + (0 + d) * 75, bihL + (0 + d) * 15, bhhL + (0 + d) * 15,
        &S[0][0][0], G, nullptr, nullptr, d, lane);
    __syncthreads();

    // L2: G -> S
    run_layer<false, T, true, false, true, false>(
        wihL + (2 + d) * 150, whhL + (2 + d) * 75, bihL + (2 + d) * 15, bhhL + (2 + d) * 15,
        G, &S[0][0][0], nullptr, nullptr, d, lane);
    __syncthreads();

    // L3: S -> G
    run_layer<false, T, true, false, false, true>(
        wihL + (4 + d) * 150, whhL + (4 + d) * 75, bihL + (4 + d) * 15, bhhL + (4 + d) * 15,
        &S[0][0][0], G, nullptr, nullptr, d, lane);
    __syncthreads();

    // L4: G -> out; fwd runs 30 steps, bwd needs only its first step
    {
        float* op = out + (base + lr) * 10 + d * 5;
        if (d == 0)
            run_layer<false, T, false, true, true, false>(
                wihL + 6 * 150, whhL + 6 * 75, bihL + 6 * 15, bhhL + 6 * 15,
                G, nullptr, nullptr, op, d, lane);
        else
            run_layer<false, 1, false, true, true, false>(
                wihL + 7 * 150, whhL + 7 * 75, bihL + 7 * 15, bhhL + 7 * 15,
                G, nullptr, nullptr, op, d, lane);
    }
}

extern "C" void kernel_launch(void* const* d_in, const int* in_sizes, int n_in,
                              void* d_out, int out_size, void* d_ws, size_t ws_size,
                              hipStream_t stream) {
    const float* x    = (const float*)d_in[0];
    const float* wih0 = (const float*)d_in[1];
    const float* whh0 = (const float*)d_in[2];
    const float* bih0 = (const float*)d_in[3];
    const float* bhh0 = (const float*)d_in[4];
    const float* wihL = (const float*)d_in[5];
    const float* whhL = (const float*)d_in[6];
    const float* bihL = (const float*)d_in[7];
    const float* bhhL = (const float*)d_in[8];
    float* out = (float*)d_out;

    gru_all<<<NBLK, 128, 0, stream>>>(x, wih0, whh0, bih0, bhh0,
                                      wihL, whhL, bihL, bhhL, out);
}